// Round 4
// baseline (415.886 us; speedup 1.0000x reference)
//
#include <hip/hip_runtime.h>
#include <stdint.h>

// KMaxPool: rows of S=4096 f32, top-K=8 values, output in original index order.
// One wave per row. R3 kernel UNCHANGED.
//
// R4 = measurement round: launch the identical kernel TWICE per kernel_launch.
// R1-R3 (three structurally disjoint kernels) all timed 356-360us total ->
// either all coincidentally ~110us, or all ~45us (roofline) with a ~310us
// harness floor. T4 - T3 isolates the kernel's own dispatch time K exactly:
// the harness floor cancels. Idempotent: 2nd dispatch re-reads pristine input,
// rewrites same output, re-inits its LDS state.
#define WPB    4
#define CAP    128
#define KK     8
#define SLEN   4096
#define CHUNKS 16

typedef const __attribute__((address_space(1))) uint32_t g_u32;
typedef __attribute__((address_space(3))) uint32_t l_u32;

__global__ __launch_bounds__(256, 2)
void kmax_kernel(const float* __restrict__ x, float* __restrict__ out, int nrows) {
    const int wave = threadIdx.x >> 6;
    const int lane = threadIdx.x & 63;
    const int row  = blockIdx.x * WPB + wave;

    __shared__ float              s_row[WPB][SLEN];   // 64 KiB
    __shared__ int                s_cnt[WPB];
    __shared__ unsigned long long s_key[WPB][CAP];    // 4 KiB

    if (row >= nrows) return;          // no barriers in kernel -> safe

    if (lane == 0) s_cnt[wave] = 0;

    // ---- async DMA row -> LDS: 16 x (64 lanes x 16 B)
    const float* gbase = x + (size_t)row * SLEN;
    float*       lbase = &s_row[wave][0];
    #pragma unroll
    for (int j = 0; j < CHUNKS; ++j) {
        __builtin_amdgcn_global_load_lds((g_u32*)(gbase + j * 256 + lane * 4),
                                         (l_u32*)(lbase + j * 256),
                                         16, 0, 0);
    }

    const float NEG_INF = __int_as_float(0xff800000);
    float m[8];
    #pragma unroll
    for (int e = 0; e < 8; ++e) m[e] = NEG_INF;

    const float4* lrow = reinterpret_cast<const float4*>(lbase);

    // ---- phase A: 8 substream running maxes per lane
    asm volatile("s_waitcnt vmcnt(8)" ::: "memory");
    #pragma unroll
    for (int j = 0; j < 8; ++j) {
        const float4 v = lrow[j * 64 + lane];
        const int b = (j & 1) * 4;
        m[b + 0] = fmaxf(m[b + 0], v.x);
        m[b + 1] = fmaxf(m[b + 1], v.y);
        m[b + 2] = fmaxf(m[b + 2], v.z);
        m[b + 3] = fmaxf(m[b + 3], v.w);
    }
    asm volatile("s_waitcnt vmcnt(0)" ::: "memory");
    #pragma unroll
    for (int j = 8; j < CHUNKS; ++j) {
        const float4 v = lrow[j * 64 + lane];
        const int b = (j & 1) * 4;
        m[b + 0] = fmaxf(m[b + 0], v.x);
        m[b + 1] = fmaxf(m[b + 1], v.y);
        m[b + 2] = fmaxf(m[b + 2], v.z);
        m[b + 3] = fmaxf(m[b + 3], v.w);
    }

    // ---- sort m[0..7] descending (Batcher, 19 CAS)
    #define MCAS(a, b) { float hi = fmaxf(m[a], m[b]); float lo = fminf(m[a], m[b]); m[a] = hi; m[b] = lo; }
    MCAS(0,1) MCAS(2,3) MCAS(4,5) MCAS(6,7)
    MCAS(0,2) MCAS(1,3) MCAS(4,6) MCAS(5,7)
    MCAS(1,2) MCAS(5,6)
    MCAS(0,4) MCAS(1,5) MCAS(2,6) MCAS(3,7)
    MCAS(2,4) MCAS(3,5)
    MCAS(1,2) MCAS(3,4) MCAS(5,6)
    #undef MCAS

    // ---- butterfly top-8 merge across 64 lanes -> exact sorted top-8 of the
    // 512 substream maxes in every lane
    #pragma unroll
    for (int s = 1; s < 64; s <<= 1) {
        float b[8], t[8];
        #pragma unroll
        for (int i = 0; i < 8; ++i) b[i] = __shfl_xor(m[i], s, 64);
        #pragma unroll
        for (int i = 0; i < 8; ++i) t[i] = fmaxf(m[i], b[7 - i]);
        #define BCAS(a, c) { float hi = fmaxf(t[a], t[c]); float lo = fminf(t[a], t[c]); t[a] = hi; t[c] = lo; }
        BCAS(0,4) BCAS(1,5) BCAS(2,6) BCAS(3,7)
        BCAS(0,2) BCAS(1,3) BCAS(4,6) BCAS(5,7)
        BCAS(0,1) BCAS(2,3) BCAS(4,5) BCAS(6,7)
        #undef BCAS
        #pragma unroll
        for (int i = 0; i < 8; ++i) m[i] = t[i];
    }
    const float Tthr = m[7];

    // ---- phase B: rescan from LDS, push packed u64 keys
    // key = (ordered(val)<<32)|(4095-idx); key desc == (val desc, idx asc)
    #pragma unroll
    for (int j = 0; j < CHUNKS; ++j) {
        const float4 v = lrow[j * 64 + lane];
        const bool p0 = v.x >= Tthr, p1 = v.y >= Tthr, p2 = v.z >= Tthr, p3 = v.w >= Tthr;
        if (p0 || p1 || p2 || p3) {
            const int base = (j * 64 + lane) * 4;
            #define PUSH(val, idx) { \
                int p = atomicAdd(&s_cnt[wave], 1); \
                if (p < CAP) { \
                    unsigned u = __float_as_uint(val); \
                    u ^= ((unsigned)((int)u >> 31)) | 0x80000000u; \
                    s_key[wave][p] = ((unsigned long long)u << 32) | (unsigned)(4095 - (idx)); \
                } }
            if (p0) PUSH(v.x, base + 0)
            if (p1) PUSH(v.y, base + 1)
            if (p2) PUSH(v.z, base + 2)
            if (p3) PUSH(v.w, base + 3)
            #undef PUSH
        }
    }

    asm volatile("s_waitcnt lgkmcnt(0)" ::: "memory");

    int n = s_cnt[wave];
    if (n > CAP) n = CAP;

    // ---- all lanes redundantly insertion-select top-8 keys
    unsigned long long kk[KK];
    #pragma unroll
    for (int i = 0; i < KK; ++i) kk[i] = 0ull;
    for (int i = 0; i < n; ++i) {
        unsigned long long c = s_key[wave][i];
        if (c > kk[7]) {
            #pragma unroll
            for (int t = 7; t > 0; --t)
                kk[t] = (c > kk[t - 1]) ? kk[t - 1] : ((c > kk[t]) ? c : kk[t]);
            kk[0] = (c > kk[0]) ? c : kk[0];
        }
    }

    // ---- reorder winners by ascending original index == descending low32
    #define ICAS(a, b) { bool sw = (unsigned)kk[a] < (unsigned)kk[b]; \
        unsigned long long hi = sw ? kk[b] : kk[a]; \
        unsigned long long lo = sw ? kk[a] : kk[b]; \
        kk[a] = hi; kk[b] = lo; }
    ICAS(0,1) ICAS(2,3) ICAS(4,5) ICAS(6,7)
    ICAS(0,2) ICAS(1,3) ICAS(4,6) ICAS(5,7)
    ICAS(1,2) ICAS(5,6)
    ICAS(0,4) ICAS(1,5) ICAS(2,6) ICAS(3,7)
    ICAS(2,4) ICAS(3,5)
    ICAS(1,2) ICAS(3,4) ICAS(5,6)
    #undef ICAS

    if (lane == 0) {
        float vals[KK];
        #pragma unroll
        for (int i = 0; i < KK; ++i) {
            unsigned g = (unsigned)(kk[i] >> 32);
            unsigned msk = ((int)g < 0) ? 0x80000000u : 0xFFFFFFFFu;
            vals[i] = __uint_as_float(g ^ msk);
        }
        float4* o = reinterpret_cast<float4*>(out + (size_t)row * KK);
        o[0] = make_float4(vals[0], vals[1], vals[2], vals[3]);
        o[1] = make_float4(vals[4], vals[5], vals[6], vals[7]);
    }
}

extern "C" void kernel_launch(void* const* d_in, const int* in_sizes, int n_in,
                              void* d_out, int out_size, void* d_ws, size_t ws_size,
                              hipStream_t stream) {
    const float* x = (const float*)d_in[0];
    float* out = (float*)d_out;
    const int nrows = out_size / KK;                 // 16 * 1024 = 16384
    const int blocks = (nrows + WPB - 1) / WPB;      // 4096
    // Launch TWICE: T4 - T3 = one kernel's dispatch time (harness floor cancels).
    kmax_kernel<<<blocks, 256, 0, stream>>>(x, out, nrows);
    kmax_kernel<<<blocks, 256, 0, stream>>>(x, out, nrows);
}

// Round 5
// 368.758 us; speedup vs baseline: 1.1278x; 1.1278x over previous
//
#include <hip/hip_runtime.h>
#include <stdint.h>

// KMaxPool: rows of S=4096 f32, top-K=8 values, output in original index order.
//
// R5: persistent-wave software pipeline. R4's double-launch experiment measured
// the kernel at K~=60us vs a ~45us memory roofline (harness floor ~296us).
// Theory: per-row serial structure (DMA -> drain -> 1.4us compute tail -> block
// exit) leaves the memory pipe empty during the synchronized compute tails and
// between block dispatches. Fix: grid = 512 blocks (exactly 2/CU, co-resident),
// each wave grid-strides over 8 rows and issues the NEXT row's 16 DMA ops
// before running the current row's selection/store tail -> 16 KiB always in
// flight per wave, memory queue never drains. All state wave-private, zero
// __syncthreads; buffer reuse is safe because selection reads only s_key.
#define WPB    4
#define CAP    128
#define KK     8
#define SLEN   4096
#define CHUNKS 16

typedef const __attribute__((address_space(1))) uint32_t g_u32;
typedef __attribute__((address_space(3))) uint32_t l_u32;

__global__ __launch_bounds__(256, 2)
void kmax_kernel(const float* __restrict__ x, float* __restrict__ out, int nrows) {
    const int wave = threadIdx.x >> 6;
    const int lane = threadIdx.x & 63;
    const int stride = gridDim.x * WPB;          // 2048 waves total

    __shared__ float              s_row[WPB][SLEN];   // 64 KiB
    __shared__ int                s_cnt[WPB];
    __shared__ unsigned long long s_key[WPB][CAP];    // 4 KiB

    const float NEG_INF = __int_as_float(0xff800000);
    float*        lbase = &s_row[wave][0];
    const float4* lrow  = reinterpret_cast<const float4*>(lbase);

    if (lane == 0) s_cnt[wave] = 0;

    int row = blockIdx.x * WPB + wave;

    // prologue: DMA first row
    if (row < nrows) {
        const float* gbase = x + (size_t)row * SLEN;
        #pragma unroll
        for (int j = 0; j < CHUNKS; ++j)
            __builtin_amdgcn_global_load_lds((g_u32*)(gbase + j * 256 + lane * 4),
                                             (l_u32*)(lbase + j * 256), 16, 0, 0);
    }

    while (row < nrows) {
        const int next = row + stride;

        // ---- phase A: 8 substream running maxes per lane, piped against DMA
        float m[8];
        #pragma unroll
        for (int e = 0; e < 8; ++e) m[e] = NEG_INF;

        asm volatile("s_waitcnt vmcnt(8)" ::: "memory");   // loads 0-7 done
        #pragma unroll
        for (int j = 0; j < 8; ++j) {
            const float4 v = lrow[j * 64 + lane];
            const int b = (j & 1) * 4;
            m[b + 0] = fmaxf(m[b + 0], v.x);
            m[b + 1] = fmaxf(m[b + 1], v.y);
            m[b + 2] = fmaxf(m[b + 2], v.z);
            m[b + 3] = fmaxf(m[b + 3], v.w);
        }
        asm volatile("s_waitcnt vmcnt(0)" ::: "memory");   // all loads done
        #pragma unroll
        for (int j = 8; j < CHUNKS; ++j) {
            const float4 v = lrow[j * 64 + lane];
            const int b = (j & 1) * 4;
            m[b + 0] = fmaxf(m[b + 0], v.x);
            m[b + 1] = fmaxf(m[b + 1], v.y);
            m[b + 2] = fmaxf(m[b + 2], v.z);
            m[b + 3] = fmaxf(m[b + 3], v.w);
        }

        // ---- sort m[0..7] descending (Batcher, 19 CAS)
        #define MCAS(a, b) { float hi = fmaxf(m[a], m[b]); float lo = fminf(m[a], m[b]); m[a] = hi; m[b] = lo; }
        MCAS(0,1) MCAS(2,3) MCAS(4,5) MCAS(6,7)
        MCAS(0,2) MCAS(1,3) MCAS(4,6) MCAS(5,7)
        MCAS(1,2) MCAS(5,6)
        MCAS(0,4) MCAS(1,5) MCAS(2,6) MCAS(3,7)
        MCAS(2,4) MCAS(3,5)
        MCAS(1,2) MCAS(3,4) MCAS(5,6)
        #undef MCAS

        // ---- butterfly top-8 merge across 64 lanes -> exact sorted top-8 of
        // the 512 substream maxes in every lane
        #pragma unroll
        for (int s = 1; s < 64; s <<= 1) {
            float b[8], t[8];
            #pragma unroll
            for (int i = 0; i < 8; ++i) b[i] = __shfl_xor(m[i], s, 64);
            #pragma unroll
            for (int i = 0; i < 8; ++i) t[i] = fmaxf(m[i], b[7 - i]);
            #define BCAS(a, c) { float hi = fmaxf(t[a], t[c]); float lo = fminf(t[a], t[c]); t[a] = hi; t[c] = lo; }
            BCAS(0,4) BCAS(1,5) BCAS(2,6) BCAS(3,7)
            BCAS(0,2) BCAS(1,3) BCAS(4,6) BCAS(5,7)
            BCAS(0,1) BCAS(2,3) BCAS(4,5) BCAS(6,7)
            #undef BCAS
            #pragma unroll
            for (int i = 0; i < 8; ++i) m[i] = t[i];
        }
        const float Tthr = m[7];   // <= true 8th-largest; >=8 elements qualify

        // ---- phase B: rescan from LDS, push packed u64 keys
        // key = (ordered(val)<<32)|(4095-idx); key desc == (val desc, idx asc)
        #pragma unroll
        for (int j = 0; j < CHUNKS; ++j) {
            const float4 v = lrow[j * 64 + lane];
            const bool p0 = v.x >= Tthr, p1 = v.y >= Tthr, p2 = v.z >= Tthr, p3 = v.w >= Tthr;
            if (p0 || p1 || p2 || p3) {
                const int base = (j * 64 + lane) * 4;
                #define PUSH(val, idx) { \
                    int p = atomicAdd(&s_cnt[wave], 1); \
                    if (p < CAP) { \
                        unsigned u = __float_as_uint(val); \
                        u ^= ((unsigned)((int)u >> 31)) | 0x80000000u; \
                        s_key[wave][p] = ((unsigned long long)u << 32) | (unsigned)(4095 - (idx)); \
                    } }
                if (p0) PUSH(v.x, base + 0)
                if (p1) PUSH(v.y, base + 1)
                if (p2) PUSH(v.z, base + 2)
                if (p3) PUSH(v.w, base + 3)
                #undef PUSH
            }
        }

        asm volatile("s_waitcnt lgkmcnt(0)" ::: "memory");
        int n = s_cnt[wave];
        if (n > CAP) n = CAP;
        if (lane == 0) s_cnt[wave] = 0;      // wave-private, DS in order: all
                                             // lanes read n above before reset

        // ---- PIPELINE: done reading s_row -> issue next row's DMA now, so it
        // streams while this wave runs the selection/store tail.
        if (next < nrows) {
            const float* gnext = x + (size_t)next * SLEN;
            #pragma unroll
            for (int j = 0; j < CHUNKS; ++j)
                __builtin_amdgcn_global_load_lds((g_u32*)(gnext + j * 256 + lane * 4),
                                                 (l_u32*)(lbase + j * 256), 16, 0, 0);
        }

        // ---- all lanes redundantly insertion-select top-8 keys (broadcast
        // LDS reads, wave-uniform control flow)
        unsigned long long kk[KK];
        #pragma unroll
        for (int i = 0; i < KK; ++i) kk[i] = 0ull;
        for (int i = 0; i < n; ++i) {
            unsigned long long c = s_key[wave][i];
            if (c > kk[7]) {
                #pragma unroll
                for (int t = 7; t > 0; --t)
                    kk[t] = (c > kk[t - 1]) ? kk[t - 1] : ((c > kk[t]) ? c : kk[t]);
                kk[0] = (c > kk[0]) ? c : kk[0];
            }
        }

        // ---- reorder winners by ascending original index == descending low32
        #define ICAS(a, b) { bool sw = (unsigned)kk[a] < (unsigned)kk[b]; \
            unsigned long long hi = sw ? kk[b] : kk[a]; \
            unsigned long long lo = sw ? kk[a] : kk[b]; \
            kk[a] = hi; kk[b] = lo; }
        ICAS(0,1) ICAS(2,3) ICAS(4,5) ICAS(6,7)
        ICAS(0,2) ICAS(1,3) ICAS(4,6) ICAS(5,7)
        ICAS(1,2) ICAS(5,6)
        ICAS(0,4) ICAS(1,5) ICAS(2,6) ICAS(3,7)
        ICAS(2,4) ICAS(3,5)
        ICAS(1,2) ICAS(3,4) ICAS(5,6)
        #undef ICAS

        if (lane == 0) {
            float vals[KK];
            #pragma unroll
            for (int i = 0; i < KK; ++i) {
                unsigned g = (unsigned)(kk[i] >> 32);
                unsigned msk = ((int)g < 0) ? 0x80000000u : 0xFFFFFFFFu;
                vals[i] = __uint_as_float(g ^ msk);
            }
            float4* o = reinterpret_cast<float4*>(out + (size_t)row * KK);
            o[0] = make_float4(vals[0], vals[1], vals[2], vals[3]);
            o[1] = make_float4(vals[4], vals[5], vals[6], vals[7]);
        }

        row = next;
    }
}

extern "C" void kernel_launch(void* const* d_in, const int* in_sizes, int n_in,
                              void* d_out, int out_size, void* d_ws, size_t ws_size,
                              hipStream_t stream) {
    const float* x = (const float*)d_in[0];
    float* out = (float*)d_out;
    const int nrows = out_size / KK;   // 16 * 1024 = 16384
    // 512 persistent blocks = exactly 2/CU (LDS-bound occupancy), all
    // co-resident; each of the 2048 waves grid-strides over 8 rows.
    kmax_kernel<<<512, 256, 0, stream>>>(x, out, nrows);
}